// Round 1
// 59.750 us; speedup vs baseline: 1.0032x; 1.0032x over previous
//
#include <hip/hip_runtime.h>
#include <math.h>
#include <utility>

#define NU_L 2000
#define NU_V 1500
#define EPSF 1e-6f
#define EPS2 1e-12f
#define PIF   3.14159265358979323846f
#define LOG2E 1.44269504088896340736f

__device__ __forceinline__ float exp2s(float x) { return __builtin_amdgcn_exp2f(x); }
__device__ __forceinline__ float rsqs(float x)  { return __builtin_amdgcn_rsqf(x); }
__device__ __forceinline__ float rcps(float x)  { return __builtin_amdgcn_rcpf(x); }
__device__ __forceinline__ float sqrts(float x) { return __builtin_amdgcn_sqrtf(x); }

// ---------------- compile-time quadrature node tables ----------------
// Same integer formulas as the previous (verified) branchy version; we store
// float(k) so u = fmaf(k, h, EPSF) is bit-identical to the prior kernel.
// Inactive lanes: w = 0, k = mid-range dummy (finite integrand, 0 contribution).
struct alignas(8) NW { float k, w; };

constexpr NW lnode(int i) {
    return i <= 29 ? NW{(float)(64 * i),     i == 0  ? 32.0f : (i == 29 ? 36.0f : 64.0f)}
         : i <= 45 ? NW{(float)(8 * i + 1624), i == 45 ? 4.5f  : 8.0f}
         : i <= 60 ? NW{(float)(i + 1939),     i == 60 ? 0.5f  : 1.0f}
         :           NW{500.0f, 0.0f};
}
constexpr NW vnode(int i) {
    return i <= 15  ? NW{(float)i,              i == 0   ? 0.5f  : (i == 15 ? 1.5f : 1.0f)}
         : i <= 31  ? NW{(float)(2 * i - 15),   i == 31  ? 3.0f  : 2.0f}
         : i <= 47  ? NW{(float)(4 * i - 77),   i == 47  ? 18.0f : 4.0f}
         : i <= 86  ? NW{(float)(32 * i - 1393), i == 86 ? 20.0f : 32.0f}
         : i <= 102 ? NW{(float)(8 * i + 671),  i == 102 ? 4.5f  : 8.0f}
         : i <= 114 ? NW{(float)(i + 1385),     i == 114 ? 0.5f  : 1.0f}
         :            NW{700.0f, 0.0f};
}

struct LTab { NW v[64]; };
struct VTab { NW v[128]; };
template <size_t... I>
constexpr LTab mkL(std::index_sequence<I...>) { return LTab{{ lnode((int)I)... }}; }
template <size_t... I>
constexpr VTab mkV(std::index_sequence<I...>) { return VTab{{ vnode((int)I)... }}; }

__device__ __constant__ LTab g_L = mkL(std::make_index_sequence<64>{});
__device__ __constant__ VTab g_V = mkV(std::make_index_sequence<128>{});

// ---------------- DPP wave-64 sum (result lands in lane 63) ----------------
// row_shr:1/2/4/8 then row_bcast:15, row_bcast:31 — full-rate VALU adds on the
// vector pipe; replaces 24 ds_bpermute (__shfl_down) DS-pipe ops + lgkm waits.
template <int CTRL>
__device__ __forceinline__ float dppadd(float x) {
    return x + __int_as_float(__builtin_amdgcn_update_dpp(
                   0, __float_as_int(x), CTRL, 0xf, 0xf, true));
}
__device__ __forceinline__ float wave_sum63(float x) {
    x = dppadd<0x111>(x);   // row_shr:1
    x = dppadd<0x112>(x);   // row_shr:2
    x = dppadd<0x114>(x);   // row_shr:4
    x = dppadd<0x118>(x);   // row_shr:8  -> lane15 of each row = row sum
    x = dppadd<0x142>(x);   // row_bcast:15 -> lane31/63 = half sums
    x = dppadd<0x143>(x);   // row_bcast:31 -> lane63 = full sum
    return x;
}

// One wave (64 lanes) per zs element: no LDS, no barriers, no DS ops.
__global__ __launch_bounds__(256) void adsbh_kernel(
    const float* __restrict__ pa, const float* __restrict__ pb,
    const float* __restrict__ zs_arr, float* __restrict__ out, int B)
{
    const int wid  = (threadIdx.x >> 6) & 3;
    const int lane = threadIdx.x & 63;
    const int zi   = blockIdx.x * 4 + wid;
    if (zi >= B) return;

    // issue the per-lane node-table loads early (latency hides under prologue)
    const NW nL  = g_L.v[lane];
    const NW nV0 = g_V.v[lane];
    const NW nV1 = g_V.v[lane + 64];

    // coefficient sets (pre-scaled by log2 e):
    //   a*: Pa (for f);  h*: Pb/2 (sqrt(g) in L);  c*: (Pa+Pb)/2 (sqrt(fg) in V)
    const float a0 = pa[0]*LOG2E, a1 = pa[1]*LOG2E, a2 = pa[2]*LOG2E,
                a3 = pa[3]*LOG2E, a4 = pa[4]*LOG2E;
    const float h0 = 0.5f*pb[0]*LOG2E, h1 = 0.5f*pb[1]*LOG2E, h2 = 0.5f*pb[2]*LOG2E,
                h3 = 0.5f*pb[3]*LOG2E, h4 = 0.5f*pb[4]*LOG2E;
    const float c0 = 0.5f*a0 + h0, c1 = 0.5f*a1 + h1, c2 = 0.5f*a2 + h2,
                c3 = 0.5f*a3 + h3, c4 = 0.5f*a4 + h4;

    const float zs  = zs_arr[zi];
    const float zs2 = zs * zs;
    const float zs4 = zs2 * zs2;
    const float Hs  = fmaf(a4, zs4, fmaf(zs2, fmaf(a3, zs, a2), fmaf(a1, zs, a0)));
    const float fzs = (1.0f - zs4) * exp2s(zs * Hs);

    const float hL = (1.0f - 2.0f * EPSF) / (float)(NU_L - 1);
    const float hV = (1.0f - 2.0f * EPSF) / (float)(NU_V - 1);

    float Lre = 0.0f, LiP = 0.0f, Vre = 0.0f, ViP = 0.0f;  // *iP = -Im

    // ---- L integrand eval, weight w (in units of hL); w=0 => masked ----
    // Reflected half-angle (P=|nx|+r) — cancellation-free in all quadrants.
    auto evalL = [&](float u, float w) {
        float z = zs*u, z2 = z*z, z4 = z2*z2;
        float omz4 = 1.0f - z4;
        float pA  = fmaf(a1, z, a0), pA2 = fmaf(a3, z, a2);
        float hA  = fmaf(z2, pA2, pA); hA = fmaf(a4, z4, hA);
        float Pa  = z * hA;
        float pH  = fmaf(h1, z, h0), pH2 = fmaf(h3, z, h2);
        float hH  = fmaf(z2, pH2, pH); hH = fmaf(h4, z4, hH);
        float PhM = fmaf(z, hH, -0.5f);          // Ph - 0.5 (folds sqrt(1/2))
        float Ea  = exp2s(Pa);
        float Eh  = exp2s(PhM);
        float fz  = omz4 * Ea;
        float A   = zs4 * fz;
        float dx  = fmaf(z4, fzs, EPSF);
        float D   = fmaf(dx, dx, EPS2);
        float t1  = fmaf(A, dx, -D);
        float nx  = fmaf(EPSF, D, t1);           // A*dx - D(1-eps)
        float ny  = EPSF * (D - A);
        float r2  = fmaf(nx, nx, ny * ny);
        float ir  = rsqs(r2);
        float r   = r2 * ir;
        float P   = fabsf(nx) + r;
        float W   = omz4 * (P * r2);
        float iW  = rcps(W);
        float S   = sqrts(D * iW);
        float SS  = (S * Eh) * w;
        float cA  = P * SS, cB = fabsf(ny) * SS;
        bool  neg = nx < 0.0f;
        float re  = neg ? cB : cA;
        float ti  = neg ? cA : cB;
        Lre += re;
        LiP += copysignf(ti, ny);
    };

    // ---- V integrand eval: term = F/csqrt(inner) - 1, then /(z^2+eps(1+i))
    auto evalV = [&](float u, float w) {
        float z = zs*u, z2 = z*z, z4 = z2*z2;
        float omz4 = 1.0f - z4;
        float pA  = fmaf(a1, z, a0), pA2 = fmaf(a3, z, a2);
        float hA  = fmaf(z2, pA2, pA); hA = fmaf(a4, z4, hA);
        float Pa  = z * hA;
        float pC  = fmaf(c1, z, c0), pC2 = fmaf(c3, z, c2);
        float hC  = fmaf(z2, pC2, pC); hC = fmaf(c4, z4, hC);
        float PcM = fmaf(z, hC, -0.5f);          // Pc - 0.5 (folds sqrt(1/2))
        float Ea  = exp2s(Pa);
        float Fs  = exp2s(PcM);
        float fz  = omz4 * Ea;
        float Bv  = z4 * fzs;
        float dx  = fmaf(zs4, fz, EPSF);
        float D   = fmaf(dx, dx, EPS2);
        float t1  = fmaf(Bv, dx, -D);
        float nx  = fmaf(EPSF, D, -t1);          // D(1+eps) - Bv*dx
        float ny  = EPSF * (Bv + D);
        float r2  = fmaf(nx, nx, ny * ny);
        float ir  = rsqs(r2);
        float r   = r2 * ir;
        float P   = fabsf(nx) + r;
        float W   = P * r2;
        float iW  = rcps(W);
        float S   = sqrts(D * iW);
        float SS  = S * Fs;
        float cA  = P * SS, cB = fabsf(ny) * SS;
        bool  neg = nx < 0.0f;
        float wre = neg ? cB : cA;
        float wti = neg ? cA : cB;
        float tre = wre - 1.0f;
        float tiP = copysignf(wti, ny);
        float ddx = z2 + EPSF;
        float idn = rcps(fmaf(ddx, ddx, EPS2));
        float re  = fmaf(tre, ddx, -(tiP * EPSF)) * idn;
        float iP  = fmaf(tiP, ddx,   tre * EPSF) * idn;
        Vre = fmaf(w, re, Vre);
        ViP = fmaf(w, iP, ViP);
    };

    // ======== L: 61 nodes, ONE round (table-driven) ========
    evalL(fmaf(nL.k, hL, EPSF), nL.w);

    // ======== V: 115 nodes, TWO rounds (table-driven) ========
    evalV(fmaf(nV0.k, hV, EPSF), nV0.w);
    evalV(fmaf(nV1.k, hV, EPSF), nV1.w);

    // ---------------- wave reduction: DPP, result in lane 63 ----------------
    Lre = wave_sum63(Lre);
    LiP = wave_sum63(LiP);
    Vre = wave_sum63(Vre);
    ViP = wave_sum63(ViP);

    if (lane == 63) {
        const float twopi = 2.0f * PIF;
        const float sL = (2.0f / PIF) * zs * hL;
        const float sV = twopi * zs * hV;
        out[0 * B + zi] =  Lre * sL;
        out[1 * B + zi] = -LiP * sL;                 // Im = -(accumulated)
        out[2 * B + zi] =  Vre * sV - twopi / zs;
        out[3 * B + zi] = -ViP * sV;
    }
}

extern "C" void kernel_launch(void* const* d_in, const int* in_sizes, int n_in,
                              void* d_out, int out_size, void* d_ws, size_t ws_size,
                              hipStream_t stream) {
    const float* a  = (const float*)d_in[0];
    const float* b  = (const float*)d_in[1];
    const float* zs = (const float*)d_in[2];
    float* out = (float*)d_out;
    const int B = in_sizes[2];
    adsbh_kernel<<<(B + 3) / 4, 256, 0, stream>>>(a, b, zs, out, B);
}